// Round 15
// baseline (246.172 us; speedup 1.0000x reference)
//
#include <hip/hip_runtime.h>

// AttentionHead: B=8, N=2048, D=1024
// qkv = x @ W^T + b ; q,k,v split ; S = qk^T/32 ; P = softmax(S) ; out = P v
// Round-15: 4-PHASE SINGLE-BARRIER mainloop (half of round-14's barrier count,
// the confirmed lever). Phase = 32 MFMA (one qa x both qb).
//   Reads: P1: buf0.{a0,b0,b1} (16)  P2: buf0.a1 (8)  P3/P4: same on buf1.
//   Stages (WAR rule: STG after barrier(p-1) => all waves' reads <= p-2 done):
//     P1:{A0,B0,B1}(t1)[buf1, read prev-P3]  P2:A1(t1)[prev-P4]
//     P3:{A0,B0,B1}(t2)[P1]                  P4:A1(t2)[P2]
//   Confirms: vmcnt(6)@P1 [prev-P4's 2, for P2's read], vmcnt(2)@P2 [P1's 6,
//   for P3], vmcnt(6)@P3, vmcnt(2)@P4. In-flight 2..8, never drains (T4).
//   Prologue: stage T0 {A0,B0,B1,A1}; vmcnt(2); barrier  -> steady state.
//   Tail: t2 wraps to 2i (same buffer, byte-identical rewrite).
// Pipeline: cvt_fused (x,W->bf16, rowsum=0) -> qkv_gemm256 (writes Q,K,V^T)
//   -> scores_gemm256 (Pu=exp(S-16) bf16 + rowsum atomics) -> pv_gemm256 (x 1/rs)
// Workspace layout (peak 198 MiB + 64 KiB):
//   [0,32MB)    x_bf          [32,38MB)  W_bf
//   [38,70MB)   Q bf16        [70,102MB) K bf16
//   [102,166MB) Pu bf16 rows stride 2048
//   [166,198MB) Vt bf16 [b][d][n]
//   [198MB,+64KB) rowsum f32[16384]

#define AS1 __attribute__((address_space(1)))
#define AS3 __attribute__((address_space(3)))

typedef __bf16 bfrag  __attribute__((ext_vector_type(8)));
typedef float  ffrag  __attribute__((ext_vector_type(4)));
typedef __bf16 bf16x4 __attribute__((ext_vector_type(4)));

// ------- fused convert: x->bf16, W->bf16, zero rowsum (must precede scores) --
__global__ __launch_bounds__(256) void cvt_fused(const float* __restrict__ x,
                                                 const float* __restrict__ W,
                                                 __bf16* __restrict__ xb,
                                                 __bf16* __restrict__ Wb,
                                                 float* __restrict__ rowsum) {
  const int gid = blockIdx.x * 256 + threadIdx.x;
  const int stride = gridDim.x * 256;
  for (int k = gid; k < 4194304; k += stride) {
    float4 v = ((const float4*)x)[k];
    bf16x4 o;
    o[0] = (__bf16)v.x; o[1] = (__bf16)v.y; o[2] = (__bf16)v.z; o[3] = (__bf16)v.w;
    ((bf16x4*)xb)[k] = o;
  }
  for (int k = gid; k < 786432; k += stride) {
    float4 v = ((const float4*)W)[k];
    bf16x4 o;
    o[0] = (__bf16)v.x; o[1] = (__bf16)v.y; o[2] = (__bf16)v.z; o[3] = (__bf16)v.w;
    ((bf16x4*)Wb)[k] = o;
  }
  for (int k = gid; k < 16384; k += stride) rowsum[k] = 0.0f;
}

// =================== 256x256 4-phase single-barrier GEMM mainloop ============
__device__ __forceinline__ void stage_half(
    const __bf16* __restrict__ Atile, const __bf16* __restrict__ Btile,
    int lda, int ldb, __bf16* lds, int tid, int te, int h) {
  const int kt = te * 64;
  const __bf16* src = (h < 2) ? Atile : Btile;
  const int ld = (h < 2) ? lda : ldb;
  const int row0 = (h & 1) * 128;
  __bf16* dst = lds + (te & 1) * 32768 + h * 8192;
#pragma unroll
  for (int l = 0; l < 2; ++l) {
    const int y = l * 4096 + tid * 8;                  // linear LDS dest (uniform base + lane*16B)
    const int r = y >> 6;                              // row within half (0..127)
    const int c = ((tid & 7) * 8) ^ ((r & 7) << 3);    // inverse-swizzled source col
    __builtin_amdgcn_global_load_lds((AS1 void*)(src + (size_t)(row0 + r) * ld + kt + c),
                                     (AS3 void*)(dst + y), 16, 0, 0);
  }
}

template <int QA>
__device__ __forceinline__ void rd_a(const __bf16* lds, int bufoff, int aRowBase,
                                     int ck0, int ck1, bfrag a[4][2]) {
#pragma unroll
  for (int m = 0; m < 4; ++m) {
    const int off = bufoff + aRowBase + QA * 8192 + m * 1024;
    a[m][0] = *(const bfrag*)&lds[off + ck0];
    a[m][1] = *(const bfrag*)&lds[off + ck1];
  }
}

template <int QB>
__device__ __forceinline__ void rd_bq(const __bf16* lds, int bufoff, int bRowBase,
                                      int ck0, int ck1, bfrag b[2][2]) {
#pragma unroll
  for (int n = 0; n < 2; ++n) {
    const int off = bufoff + bRowBase + QB * 8192 + n * 1024;
    b[n][0] = *(const bfrag*)&lds[off + ck0];
    b[n][1] = *(const bfrag*)&lds[off + ck1];
  }
}

// Phase tail: vmcnt(VMC); barrier; lgkm(0); setprio(1); 32 MFMA (qa x both qb).
#define PH2(QA, VMC)                                                           \
  {                                                                            \
    asm volatile("s_waitcnt vmcnt(" #VMC ")" ::: "memory");                    \
    __builtin_amdgcn_s_barrier();                                              \
    asm volatile("s_waitcnt lgkmcnt(0)" ::: "memory");                         \
    __builtin_amdgcn_s_setprio(1);                                             \
    _Pragma("unroll") for (int m_ = 0; m_ < 4; ++m_)                           \
    _Pragma("unroll") for (int n_ = 0; n_ < 2; ++n_)                           \
    _Pragma("unroll") for (int ks_ = 0; ks_ < 2; ++ks_) {                      \
      acc[(QA) * 4 + m_][n_] = __builtin_amdgcn_mfma_f32_16x16x32_bf16(        \
          a[m_][ks_], b0f[n_][ks_], acc[(QA) * 4 + m_][n_], 0, 0, 0);          \
      acc[(QA) * 4 + m_][2 + n_] = __builtin_amdgcn_mfma_f32_16x16x32_bf16(    \
          a[m_][ks_], b1f[n_][ks_], acc[(QA) * 4 + m_][2 + n_], 0, 0, 0);      \
    }                                                                          \
    __builtin_amdgcn_s_setprio(0);                                             \
  }

#define STG(TE, H) stage_half(Atile, Btile, lda, ldb, lds, tid, (TE), (H))

__device__ __forceinline__ void gemm256_mainloop(
    const __bf16* __restrict__ Atile, const __bf16* __restrict__ Btile,
    int lda, int ldb, int K, __bf16* lds, ffrag acc[8][4]) {
  const int tid  = threadIdx.x;
  const int lane = tid & 63;
  const int wid  = tid >> 6;
  const int wr   = wid >> 2, wc = wid & 3;
  const int fr   = lane & 15;
  const int fk   = (lane >> 4) * 8;
  const int swz  = (fr & 7) << 3;
  const int ck0  = fk ^ swz;            // ks=0 frag col (swizzled)
  const int ck1  = (32 + fk) ^ swz;     // ks=1
  const int aRowBase = (wr * 64 + fr) * 64;
  const int bRowBase = 16384 + (wc * 32 + fr) * 64;
  const int nT = K >> 6;

  // prologue: T0 {A0,B0,B1,A1}. vmcnt(2) -> {A0,B0,B1} confirmed (A1 in flight)
  STG(0, 0); STG(0, 2); STG(0, 3); STG(0, 1);
  asm volatile("s_waitcnt vmcnt(2)" ::: "memory");
  __builtin_amdgcn_s_barrier();

  const int nIter = nT >> 1;
#pragma unroll 1
  for (int i = 0; i < nIter; ++i) {
    const int t1  = 2 * i + 1;                                     // always < nT
    const int t2e = (2 * i + 2 < nT) ? (2 * i + 2) : (2 * i);      // tail wrap, same parity
    bfrag a[4][2], b0f[2][2], b1f[2][2];
    // P1: read a0,b0,b1 (buf0); stage {A0,B0,B1}(t1); vmcnt(6) covers prev-P4's A1
    rd_a<0>(lds, 0, aRowBase, ck0, ck1, a);
    rd_bq<0>(lds, 0, bRowBase, ck0, ck1, b0f);
    rd_bq<1>(lds, 0, bRowBase, ck0, ck1, b1f);
    STG(t1, 0); STG(t1, 2); STG(t1, 3);
    PH2(0, 6)
    // P2: read a1 (buf0); stage A1(t1); vmcnt(2) covers P1's 6 (for P3's reads)
    rd_a<1>(lds, 0, aRowBase, ck0, ck1, a);
    STG(t1, 1);
    PH2(1, 2)
    // P3: read a0,b0,b1 (buf1); stage {A0,B0,B1}(t2); vmcnt(6) covers P2's 2
    rd_a<0>(lds, 32768, aRowBase, ck0, ck1, a);
    rd_bq<0>(lds, 32768, bRowBase, ck0, ck1, b0f);
    rd_bq<1>(lds, 32768, bRowBase, ck0, ck1, b1f);
    STG(t2e, 0); STG(t2e, 2); STG(t2e, 3);
    PH2(0, 6)
    // P4: read a1 (buf1); stage A1(t2); vmcnt(2) covers P3's 6 (for next-P1)
    rd_a<1>(lds, 32768, aRowBase, ck0, ck1, a);
    STG(t2e, 1);
    PH2(1, 2)
  }
}

#define ACC_ZERO()                                                             \
  ffrag acc[8][4];                                                             \
  _Pragma("unroll") for (int m = 0; m < 8; ++m)                                \
  _Pragma("unroll") for (int n = 0; n < 4; ++n) acc[m][n] = (ffrag)(0.0f);

// Epilogue mapping for acc[i][j]: qa=i>>2, m=i&3, qb=j>>1, n=j&1.
// row = brow + qa*128 + wr*64 + m*16 + (lane>>4)*4 + r
// col = bcol + qb*128 + wc*32 + n*16 + (lane&15)

// ---------------- kernel 1: qkv projection (V written transposed) ----------
__global__ __launch_bounds__(512, 1) void qkv_gemm256(
    const __bf16* __restrict__ Abf, const __bf16* __restrict__ Wbf,
    const float* __restrict__ bias,
    __bf16* __restrict__ Q, __bf16* __restrict__ Ko, __bf16* __restrict__ Vt) {
  __shared__ __bf16 lds[65536];
  ACC_ZERO();
  int bid = (int)blockIdx.x;
  bid = (bid & 7) * 96 + (bid >> 3);          // XCD swizzle (768 % 8 == 0, bijective)
  const int brow = (bid / 12) * 256;
  const int bcol = (bid % 12) * 256;
  gemm256_mainloop(Abf + (size_t)brow * 1024, Wbf + (size_t)bcol * 1024,
                   1024, 1024, 1024, lds, acc);
  const int lane = threadIdx.x & 63, wid = threadIdx.x >> 6;
  const int wr = wid >> 2, wc = wid & 3;
  const int region = bcol >> 10;              // 0=Q,1=K,2=V (tile within one region)
  if (region < 2) {
    __bf16* dst = region == 0 ? Q : Ko;
    const float scale = region == 0 ? 0.03125f : 1.0f;  // fold 1/sqrt(1024) into Q
#pragma unroll
    for (int j = 0; j < 4; ++j) {
      const int qb = j >> 1, n = j & 1;
      const int col = bcol + qb * 128 + wc * 32 + n * 16 + (lane & 15);
      const int o = col & 1023;
      const float bv = bias[col];
#pragma unroll
      for (int i = 0; i < 8; ++i) {
        const int qa = i >> 2, m = i & 3;
#pragma unroll
        for (int r = 0; r < 4; ++r) {
          const int mg = brow + qa * 128 + wr * 64 + m * 16 + (lane >> 4) * 4 + r;
          dst[(size_t)mg * 1024 + o] = (__bf16)((acc[i][j][r] + bv) * scale);
        }
      }
    }
  } else {
    // V: write transposed Vt[b][d][n]; 4 consecutive n-rows pack into one 8B store
#pragma unroll
    for (int j = 0; j < 4; ++j) {
      const int qb = j >> 1, n = j & 1;
      const int col = bcol + qb * 128 + wc * 32 + n * 16 + (lane & 15);
      const int o = col & 1023;                // d index
      const float bv = bias[col];
#pragma unroll
      for (int i = 0; i < 8; ++i) {
        const int qa = i >> 2, m = i & 3;
        const int mg0 = brow + qa * 128 + wr * 64 + m * 16 + (lane >> 4) * 4;
        const int b = mg0 >> 11, nr = mg0 & 2047;
        bf16x4 v;
#pragma unroll
        for (int r = 0; r < 4; ++r) v[r] = (__bf16)(acc[i][j][r] + bv);
        *(bf16x4*)&Vt[(size_t)b * 2097152 + (size_t)o * 2048 + nr] = v;
      }
    }
  }
}

// ------- kernel 2: Pu = exp(QK^T/32 - 16) bf16 + row-sum atomics -----------
__global__ __launch_bounds__(512, 1) void scores_gemm256(const __bf16* __restrict__ Q,
                                                         const __bf16* __restrict__ Kb,
                                                         __bf16* __restrict__ Pu,
                                                         float* __restrict__ rowsum) {
  __shared__ __bf16 lds[65536];
  ACC_ZERO();
  int bid = (int)blockIdx.x;                  // 512 blocks: XCD swizzle, batch-per-XCD
  const int wg = (bid & 7) * 64 + (bid >> 3);
  const int brow = (wg & 7) * 256, bcol = ((wg >> 3) & 7) * 256, z = wg >> 6;
  gemm256_mainloop(Q + (size_t)z * 2048 * 1024 + (size_t)brow * 1024,
                   Kb + (size_t)z * 2048 * 1024 + (size_t)bcol * 1024,
                   1024, 1024, 1024, lds, acc);
  const int lane = threadIdx.x & 63, wid = threadIdx.x >> 6;
  const int wr = wid >> 2, wc = wid & 3;
  const int fr = lane & 15, g4 = (lane >> 4) * 4;
#pragma unroll
  for (int i = 0; i < 8; ++i) {
    const int qa = i >> 2, m = i & 3;
#pragma unroll
    for (int r = 0; r < 4; ++r) {
      const int mg = brow + qa * 128 + wr * 64 + m * 16 + g4 + r;
      float part = 0.0f;
#pragma unroll
      for (int j = 0; j < 4; ++j) {
        const int qb = j >> 1, n = j & 1;
        const int o = bcol + qb * 128 + wc * 32 + n * 16 + fr;
        const float e = __expf(acc[i][j][r] - 16.0f);   // |S|<~6 -> e in bf16 range
        part += e;
        Pu[((size_t)(z * 2048 + mg)) * 2048 + o] = (__bf16)e;
      }
      // reduce the wave's 64-col partial across the 16 lanes sharing this row
      part += __shfl_xor(part, 1, 64);
      part += __shfl_xor(part, 2, 64);
      part += __shfl_xor(part, 4, 64);
      part += __shfl_xor(part, 8, 64);
      if (fr == 0) atomicAdd(&rowsum[z * 2048 + mg], part);
    }
  }
}

// ------- kernel 3: out = (Pu @ V) * 1/rowsum  (via Vt, B^T form) -----------
__global__ __launch_bounds__(512, 1) void pv_gemm256(const __bf16* __restrict__ P,
                                                     const __bf16* __restrict__ Vt,
                                                     const float* __restrict__ rowsum,
                                                     float* __restrict__ O) {
  __shared__ __bf16 lds[65536];
  ACC_ZERO();
  int bid = (int)blockIdx.x;                  // 256 blocks: XCD swizzle, batch-per-XCD
  const int wg = (bid & 7) * 32 + (bid >> 3);
  const int brow = (wg & 7) * 256, bcol = ((wg >> 3) & 3) * 256, z = wg >> 5;
  gemm256_mainloop(P + (size_t)(z * 2048 + brow) * 2048,
                   Vt + (size_t)z * 1024 * 2048 + (size_t)bcol * 2048,
                   2048, 2048, 2048, lds, acc);
  const int lane = threadIdx.x & 63, wid = threadIdx.x >> 6;
  const int wr = wid >> 2, wc = wid & 3;
  const int fr = lane & 15, g4 = (lane >> 4) * 4;
#pragma unroll
  for (int i = 0; i < 8; ++i) {
    const int qa = i >> 2, m = i & 3;
#pragma unroll
    for (int r = 0; r < 4; ++r) {
      const int mg = brow + qa * 128 + wr * 64 + m * 16 + g4 + r;
      const float inv = 1.0f / rowsum[z * 2048 + mg];
#pragma unroll
      for (int j = 0; j < 4; ++j) {
        const int qb = j >> 1, n = j & 1;
        const int o = bcol + qb * 128 + wc * 32 + n * 16 + fr;
        O[((size_t)(z * 2048 + mg)) * 1024 + o] = acc[i][j][r] * inv;
      }
    }
  }
}

extern "C" void kernel_launch(void* const* d_in, const int* in_sizes, int n_in,
                              void* d_out, int out_size, void* d_ws, size_t ws_size,
                              hipStream_t stream) {
  (void)in_sizes; (void)n_in; (void)out_size; (void)ws_size;
  const float* x    = (const float*)d_in[0];
  const float* W    = (const float*)d_in[1];
  const float* bias = (const float*)d_in[2];
  float* out = (float*)d_out;
  char* ws = (char*)d_ws;
  const size_t MB = 1u << 20;
  __bf16* x_bf = (__bf16*)(ws + 0);
  __bf16* W_bf = (__bf16*)(ws + 32 * MB);
  __bf16* Qb   = (__bf16*)(ws + 38 * MB);
  __bf16* Kb   = (__bf16*)(ws + 70 * MB);
  __bf16* Pu   = (__bf16*)(ws + 102 * MB);   // exp(S-16) bf16
  __bf16* Vt   = (__bf16*)(ws + 166 * MB);   // V^T, written by qkv epilogue
  float* rowsum = (float*)(ws + 198 * MB);   // f32[16384], zeroed by cvt_fused

  cvt_fused<<<2048, 256, 0, stream>>>(x, W, x_bf, W_bf, rowsum);
  qkv_gemm256<<<768, 512, 0, stream>>>(x_bf, W_bf, bias, Qb, Kb, Vt);
  scores_gemm256<<<512, 512, 0, stream>>>(Qb, Kb, Pu, rowsum);
  pv_gemm256<<<256, 512, 0, stream>>>(Pu, Vt, rowsum, out);
}

// Round 16
// 242.363 us; speedup vs baseline: 1.0157x; 1.0157x over previous
//
#include <hip/hip_runtime.h>

// AttentionHead: B=8, N=2048, D=1024
// qkv = x @ W^T + b ; q,k,v split ; S = qk^T/32 ; P = softmax(S) ; out = P v
// Round-16 = round-14 (best, 245.9us: 8-phase SINGLE-BARRIER, vmcnt(6)@P4/P8)
// MINUS the per-phase lgkmcnt(0) drain: ds_reads are C++ loads, the compiler
// emits fine-grained per-MFMA lgkmcnt, so MFMA#1 starts when frag#1 lands.
// Safety (traced): RAW — reads(p+1) can't hoist above the confirming vmcnt asm
// ("memory" clobber) nor above stages(p) (LDS may-alias); WAR — reads(p) are
// all consumed by end of MFMA(p) < barrier(p+1) < stage(p+2) (gap-2 rule holds
// without the drain). Round-15's 4-phase/vmcnt(2) variant reverted (neutral).
// Stage slots: P1:A1(t1) P3:A0(t2) P4:B0,B1(t2) P5:A1(t2) P7:A0,B0(t3) P8:B1(t3).
// Pipeline: cvt_fused (x,W->bf16, rowsum=0) -> qkv_gemm256 (writes Q,K,V^T)
//   -> scores_gemm256 (Pu=exp(S-16) bf16 + rowsum atomics) -> pv_gemm256 (x 1/rs)
// Workspace layout (peak 198 MiB + 64 KiB):
//   [0,32MB)    x_bf          [32,38MB)  W_bf
//   [38,70MB)   Q bf16        [70,102MB) K bf16
//   [102,166MB) Pu bf16 rows stride 2048
//   [166,198MB) Vt bf16 [b][d][n]
//   [198MB,+64KB) rowsum f32[16384]

#define AS1 __attribute__((address_space(1)))
#define AS3 __attribute__((address_space(3)))

typedef __bf16 bfrag  __attribute__((ext_vector_type(8)));
typedef float  ffrag  __attribute__((ext_vector_type(4)));
typedef __bf16 bf16x4 __attribute__((ext_vector_type(4)));

// ------- fused convert: x->bf16, W->bf16, zero rowsum (must precede scores) --
__global__ __launch_bounds__(256) void cvt_fused(const float* __restrict__ x,
                                                 const float* __restrict__ W,
                                                 __bf16* __restrict__ xb,
                                                 __bf16* __restrict__ Wb,
                                                 float* __restrict__ rowsum) {
  const int gid = blockIdx.x * 256 + threadIdx.x;
  const int stride = gridDim.x * 256;
  for (int k = gid; k < 4194304; k += stride) {
    float4 v = ((const float4*)x)[k];
    bf16x4 o;
    o[0] = (__bf16)v.x; o[1] = (__bf16)v.y; o[2] = (__bf16)v.z; o[3] = (__bf16)v.w;
    ((bf16x4*)xb)[k] = o;
  }
  for (int k = gid; k < 786432; k += stride) {
    float4 v = ((const float4*)W)[k];
    bf16x4 o;
    o[0] = (__bf16)v.x; o[1] = (__bf16)v.y; o[2] = (__bf16)v.z; o[3] = (__bf16)v.w;
    ((bf16x4*)Wb)[k] = o;
  }
  for (int k = gid; k < 16384; k += stride) rowsum[k] = 0.0f;
}

// =================== 256x256 8-phase single-barrier GEMM mainloop ============
__device__ __forceinline__ void stage_half(
    const __bf16* __restrict__ Atile, const __bf16* __restrict__ Btile,
    int lda, int ldb, __bf16* lds, int tid, int te, int h) {
  const int kt = te * 64;
  const __bf16* src = (h < 2) ? Atile : Btile;
  const int ld = (h < 2) ? lda : ldb;
  const int row0 = (h & 1) * 128;
  __bf16* dst = lds + (te & 1) * 32768 + h * 8192;
#pragma unroll
  for (int l = 0; l < 2; ++l) {
    const int y = l * 4096 + tid * 8;                  // linear LDS dest (uniform base + lane*16B)
    const int r = y >> 6;                              // row within half (0..127)
    const int c = ((tid & 7) * 8) ^ ((r & 7) << 3);    // inverse-swizzled source col
    __builtin_amdgcn_global_load_lds((AS1 void*)(src + (size_t)(row0 + r) * ld + kt + c),
                                     (AS3 void*)(dst + y), 16, 0, 0);
  }
}

template <int QA>
__device__ __forceinline__ void rd_a(const __bf16* lds, int bufoff, int aRowBase,
                                     int ck0, int ck1, bfrag a[4][2]) {
#pragma unroll
  for (int m = 0; m < 4; ++m) {
    const int off = bufoff + aRowBase + QA * 8192 + m * 1024;
    a[m][0] = *(const bfrag*)&lds[off + ck0];
    a[m][1] = *(const bfrag*)&lds[off + ck1];
  }
}

template <int QB>
__device__ __forceinline__ void rd_bq(const __bf16* lds, int bufoff, int bRowBase,
                                      int ck0, int ck1, bfrag b[2][2]) {
#pragma unroll
  for (int n = 0; n < 2; ++n) {
    const int off = bufoff + bRowBase + QB * 8192 + n * 1024;
    b[n][0] = *(const bfrag*)&lds[off + ck0];
    b[n][1] = *(const bfrag*)&lds[off + ck1];
  }
}

// Single-barrier phase tail: [vmcnt(6)] barrier; setprio 16 MFMA (compiler
// inserts fine-grained lgkmcnt per MFMA operand — no blanket drain).
#define PH(QA, QB, BREG, DOVM)                                                 \
  {                                                                            \
    if (DOVM) asm volatile("s_waitcnt vmcnt(6)" ::: "memory");                 \
    __builtin_amdgcn_s_barrier();                                              \
    __builtin_amdgcn_s_setprio(1);                                             \
    _Pragma("unroll") for (int m_ = 0; m_ < 4; ++m_)                           \
    _Pragma("unroll") for (int n_ = 0; n_ < 2; ++n_)                           \
    _Pragma("unroll") for (int ks_ = 0; ks_ < 2; ++ks_)                        \
      acc[(QA) * 4 + m_][(QB) * 2 + n_] =                                      \
          __builtin_amdgcn_mfma_f32_16x16x32_bf16(                             \
              a[m_][ks_], BREG[n_][ks_], acc[(QA) * 4 + m_][(QB) * 2 + n_],    \
              0, 0, 0);                                                        \
    __builtin_amdgcn_s_setprio(0);                                             \
  }

#define STG(TE, H) stage_half(Atile, Btile, lda, ldb, lds, tid, (TE), (H))

__device__ __forceinline__ void gemm256_mainloop(
    const __bf16* __restrict__ Atile, const __bf16* __restrict__ Btile,
    int lda, int ldb, int K, __bf16* lds, ffrag acc[8][4]) {
  const int tid  = threadIdx.x;
  const int lane = tid & 63;
  const int wid  = tid >> 6;
  const int wr   = wid >> 2, wc = wid & 3;
  const int fr   = lane & 15;
  const int fk   = (lane >> 4) * 8;
  const int swz  = (fr & 7) << 3;
  const int ck0  = fk ^ swz;            // ks=0 frag col (swizzled)
  const int ck1  = (32 + fk) ^ swz;     // ks=1
  const int aRowBase = (wr * 64 + fr) * 64;
  const int bRowBase = 16384 + (wc * 32 + fr) * 64;
  const int nT = K >> 6;

  // prologue: A0,B0,B1,A1 of T0; A0,B0,B1 of T1. vmcnt(6) -> T0 confirmed;
  // T1's 6 halves stay in flight (steady-state entry).
  STG(0, 0); STG(0, 2); STG(0, 3); STG(0, 1);
  STG(1, 0); STG(1, 2); STG(1, 3);
  asm volatile("s_waitcnt vmcnt(6)" ::: "memory");
  __builtin_amdgcn_s_barrier();

  const int nIter = nT >> 1;
#pragma unroll 1
  for (int i = 0; i < nIter; ++i) {
    const int t1  = 2 * i + 1;
    const int t2e = (2 * i + 2 < nT) ? (2 * i + 2) : (2 * i);      // tail wrap,
    const int t3e = (2 * i + 3 < nT) ? (2 * i + 3) : (2 * i + 1);  // same parity
    bfrag a[4][2], b0f[2][2], b1f[2][2];
    // P1: read a0+b0 (buf0); stage A1(t1) [buf1.A1, last read prev-P7: gap 2]
    rd_a<0>(lds, 0, aRowBase, ck0, ck1, a);
    rd_bq<0>(lds, 0, bRowBase, ck0, ck1, b0f);
    STG(t1, 1);
    PH(0, 0, b0f, false)
    // P2: read b1 (buf0); no stage
    rd_bq<1>(lds, 0, bRowBase, ck0, ck1, b1f);
    PH(0, 1, b1f, false)
    // P3: read a1 (buf0); stage A0(t2) [buf0.A0, read P1: gap 2]
    rd_a<1>(lds, 0, aRowBase, ck0, ck1, a);
    STG(t2e, 0);
    PH(1, 1, b1f, false)
    // P4: stage B0(t2) [read P1], B1(t2) [read P2]; vmcnt(6) -> T1 confirmed
    STG(t2e, 2);
    STG(t2e, 3);
    PH(1, 0, b0f, true)
    // P5: read a0+b0 (buf1); stage A1(t2) [buf0.A1, read P3: gap 2]
    rd_a<0>(lds, 32768, aRowBase, ck0, ck1, a);
    rd_bq<0>(lds, 32768, bRowBase, ck0, ck1, b0f);
    STG(t2e, 1);
    PH(0, 0, b0f, false)
    // P6: read b1 (buf1); no stage
    rd_bq<1>(lds, 32768, bRowBase, ck0, ck1, b1f);
    PH(0, 1, b1f, false)
    // P7: read a1 (buf1); stage A0(t3), B0(t3) [buf1.{A0,B0}, read P5: gap 2]
    rd_a<1>(lds, 32768, aRowBase, ck0, ck1, a);
    STG(t3e, 0);
    STG(t3e, 2);
    PH(1, 1, b1f, false)
    // P8: stage B1(t3) [read P6: gap 2]; vmcnt(6) -> t2 fully confirmed
    STG(t3e, 3);
    PH(1, 0, b0f, true)
  }
}

#define ACC_ZERO()                                                             \
  ffrag acc[8][4];                                                             \
  _Pragma("unroll") for (int m = 0; m < 8; ++m)                                \
  _Pragma("unroll") for (int n = 0; n < 4; ++n) acc[m][n] = (ffrag)(0.0f);

// Epilogue mapping for acc[i][j]: qa=i>>2, m=i&3, qb=j>>1, n=j&1.
// row = brow + qa*128 + wr*64 + m*16 + (lane>>4)*4 + r
// col = bcol + qb*128 + wc*32 + n*16 + (lane&15)

// ---------------- kernel 1: qkv projection (V written transposed) ----------
__global__ __launch_bounds__(512, 1) void qkv_gemm256(
    const __bf16* __restrict__ Abf, const __bf16* __restrict__ Wbf,
    const float* __restrict__ bias,
    __bf16* __restrict__ Q, __bf16* __restrict__ Ko, __bf16* __restrict__ Vt) {
  __shared__ __bf16 lds[65536];
  ACC_ZERO();
  int bid = (int)blockIdx.x;
  bid = (bid & 7) * 96 + (bid >> 3);          // XCD swizzle (768 % 8 == 0, bijective)
  const int brow = (bid / 12) * 256;
  const int bcol = (bid % 12) * 256;
  gemm256_mainloop(Abf + (size_t)brow * 1024, Wbf + (size_t)bcol * 1024,
                   1024, 1024, 1024, lds, acc);
  const int lane = threadIdx.x & 63, wid = threadIdx.x >> 6;
  const int wr = wid >> 2, wc = wid & 3;
  const int region = bcol >> 10;              // 0=Q,1=K,2=V (tile within one region)
  if (region < 2) {
    __bf16* dst = region == 0 ? Q : Ko;
    const float scale = region == 0 ? 0.03125f : 1.0f;  // fold 1/sqrt(1024) into Q
#pragma unroll
    for (int j = 0; j < 4; ++j) {
      const int qb = j >> 1, n = j & 1;
      const int col = bcol + qb * 128 + wc * 32 + n * 16 + (lane & 15);
      const int o = col & 1023;
      const float bv = bias[col];
#pragma unroll
      for (int i = 0; i < 8; ++i) {
        const int qa = i >> 2, m = i & 3;
#pragma unroll
        for (int r = 0; r < 4; ++r) {
          const int mg = brow + qa * 128 + wr * 64 + m * 16 + (lane >> 4) * 4 + r;
          dst[(size_t)mg * 1024 + o] = (__bf16)((acc[i][j][r] + bv) * scale);
        }
      }
    }
  } else {
    // V: write transposed Vt[b][d][n]; 4 consecutive n-rows pack into one 8B store
#pragma unroll
    for (int j = 0; j < 4; ++j) {
      const int qb = j >> 1, n = j & 1;
      const int col = bcol + qb * 128 + wc * 32 + n * 16 + (lane & 15);
      const int o = col & 1023;                // d index
      const float bv = bias[col];
#pragma unroll
      for (int i = 0; i < 8; ++i) {
        const int qa = i >> 2, m = i & 3;
        const int mg0 = brow + qa * 128 + wr * 64 + m * 16 + (lane >> 4) * 4;
        const int b = mg0 >> 11, nr = mg0 & 2047;
        bf16x4 v;
#pragma unroll
        for (int r = 0; r < 4; ++r) v[r] = (__bf16)(acc[i][j][r] + bv);
        *(bf16x4*)&Vt[(size_t)b * 2097152 + (size_t)o * 2048 + nr] = v;
      }
    }
  }
}

// ------- kernel 2: Pu = exp(QK^T/32 - 16) bf16 + row-sum atomics -----------
__global__ __launch_bounds__(512, 1) void scores_gemm256(const __bf16* __restrict__ Q,
                                                         const __bf16* __restrict__ Kb,
                                                         __bf16* __restrict__ Pu,
                                                         float* __restrict__ rowsum) {
  __shared__ __bf16 lds[65536];
  ACC_ZERO();
  int bid = (int)blockIdx.x;                  // 512 blocks: XCD swizzle, batch-per-XCD
  const int wg = (bid & 7) * 64 + (bid >> 3);
  const int brow = (wg & 7) * 256, bcol = ((wg >> 3) & 7) * 256, z = wg >> 6;
  gemm256_mainloop(Q + (size_t)z * 2048 * 1024 + (size_t)brow * 1024,
                   Kb + (size_t)z * 2048 * 1024 + (size_t)bcol * 1024,
                   1024, 1024, 1024, lds, acc);
  const int lane = threadIdx.x & 63, wid = threadIdx.x >> 6;
  const int wr = wid >> 2, wc = wid & 3;
  const int fr = lane & 15, g4 = (lane >> 4) * 4;
#pragma unroll
  for (int i = 0; i < 8; ++i) {
    const int qa = i >> 2, m = i & 3;
#pragma unroll
    for (int r = 0; r < 4; ++r) {
      const int mg = brow + qa * 128 + wr * 64 + m * 16 + g4 + r;
      float part = 0.0f;
#pragma unroll
      for (int j = 0; j < 4; ++j) {
        const int qb = j >> 1, n = j & 1;
        const int o = bcol + qb * 128 + wc * 32 + n * 16 + fr;
        const float e = __expf(acc[i][j][r] - 16.0f);   // |S|<~6 -> e in bf16 range
        part += e;
        Pu[((size_t)(z * 2048 + mg)) * 2048 + o] = (__bf16)e;
      }
      // reduce the wave's 64-col partial across the 16 lanes sharing this row
      part += __shfl_xor(part, 1, 64);
      part += __shfl_xor(part, 2, 64);
      part += __shfl_xor(part, 4, 64);
      part += __shfl_xor(part, 8, 64);
      if (fr == 0) atomicAdd(&rowsum[z * 2048 + mg], part);
    }
  }
}

// ------- kernel 3: out = (Pu @ V) * 1/rowsum  (via Vt, B^T form) -----------
__global__ __launch_bounds__(512, 1) void pv_gemm256(const __bf16* __restrict__ P,
                                                     const __bf16* __restrict__ Vt,
                                                     const float* __restrict__ rowsum,
                                                     float* __restrict__ O) {
  __shared__ __bf16 lds[65536];
  ACC_ZERO();
  int bid = (int)blockIdx.x;                  // 256 blocks: XCD swizzle, batch-per-XCD
  const int wg = (bid & 7) * 32 + (bid >> 3);
  const int brow = (wg & 7) * 256, bcol = ((wg >> 3) & 3) * 256, z = wg >> 5;
  gemm256_mainloop(P + (size_t)(z * 2048 + brow) * 2048,
                   Vt + (size_t)z * 1024 * 2048 + (size_t)bcol * 2048,
                   2048, 2048, 2048, lds, acc);
  const int lane = threadIdx.x & 63, wid = threadIdx.x >> 6;
  const int wr = wid >> 2, wc = wid & 3;
  const int fr = lane & 15, g4 = (lane >> 4) * 4;
#pragma unroll
  for (int i = 0; i < 8; ++i) {
    const int qa = i >> 2, m = i & 3;
#pragma unroll
    for (int r = 0; r < 4; ++r) {
      const int mg = brow + qa * 128 + wr * 64 + m * 16 + g4 + r;
      const float inv = 1.0f / rowsum[z * 2048 + mg];
#pragma unroll
      for (int j = 0; j < 4; ++j) {
        const int qb = j >> 1, n = j & 1;
        const int o = bcol + qb * 128 + wc * 32 + n * 16 + fr;
        O[((size_t)(z * 2048 + mg)) * 1024 + o] = acc[i][j][r] * inv;
      }
    }
  }
}

extern "C" void kernel_launch(void* const* d_in, const int* in_sizes, int n_in,
                              void* d_out, int out_size, void* d_ws, size_t ws_size,
                              hipStream_t stream) {
  (void)in_sizes; (void)n_in; (void)out_size; (void)ws_size;
  const float* x    = (const float*)d_in[0];
  const float* W    = (const float*)d_in[1];
  const float* bias = (const float*)d_in[2];
  float* out = (float*)d_out;
  char* ws = (char*)d_ws;
  const size_t MB = 1u << 20;
  __bf16* x_bf = (__bf16*)(ws + 0);
  __bf16* W_bf = (__bf16*)(ws + 32 * MB);
  __bf16* Qb   = (__bf16*)(ws + 38 * MB);
  __bf16* Kb   = (__bf16*)(ws + 70 * MB);
  __bf16* Pu   = (__bf16*)(ws + 102 * MB);   // exp(S-16) bf16
  __bf16* Vt   = (__bf16*)(ws + 166 * MB);   // V^T, written by qkv epilogue
  float* rowsum = (float*)(ws + 198 * MB);   // f32[16384], zeroed by cvt_fused

  cvt_fused<<<2048, 256, 0, stream>>>(x, W, x_bf, W_bf, rowsum);
  qkv_gemm256<<<768, 512, 0, stream>>>(x_bf, W_bf, bias, Qb, Kb, Vt);
  scores_gemm256<<<512, 512, 0, stream>>>(Qb, Kb, Pu, rowsum);
  pv_gemm256<<<256, 512, 0, stream>>>(Pu, Vt, rowsum, out);
}

// Round 17
// 238.869 us; speedup vs baseline: 1.0306x; 1.0146x over previous
//
#include <hip/hip_runtime.h>

// AttentionHead: B=8, N=2048, D=1024
// qkv = x @ W^T + b ; q,k,v split ; S = qk^T/32 ; P = softmax(S) ; out = P v
// Round-17 = round-16 (242.4us) + qkv L2-LOCALITY BLOCK ORDER: the 32
// co-resident blocks per XCD now form an 8-brow x 4-bcol supertile (live set
// 8 A-panels + 4 W-panels, streaming K in near-lockstep -> instantaneous
// working set ~400KB << 4MB L2), replacing the old ~2.7x12 pattern whose
// 7.5MB live set thrashed W and turned vmcnt(6) waits into HBM-latency waits.
// GEMM mainloop: 8-phase SINGLE-BARRIER, vmcnt(6)@P4/P8, no lgkm drain
// (compiler emits fine-grained per-MFMA lgkmcnt). Stage slots:
// P1:A1(t1) P3:A0(t2) P4:B0,B1(t2) P5:A1(t2) P7:A0,B0(t3) P8:B1(t3).
// Pipeline: cvt_fused (x,W->bf16, rowsum=0) -> qkv_gemm256 (writes Q,K,V^T)
//   -> scores_gemm256 (Pu=exp(S-16) bf16 + rowsum atomics) -> pv_gemm256 (x 1/rs)
// Workspace layout (peak 198 MiB + 64 KiB):
//   [0,32MB)    x_bf          [32,38MB)  W_bf
//   [38,70MB)   Q bf16        [70,102MB) K bf16
//   [102,166MB) Pu bf16 rows stride 2048
//   [166,198MB) Vt bf16 [b][d][n]
//   [198MB,+64KB) rowsum f32[16384]

#define AS1 __attribute__((address_space(1)))
#define AS3 __attribute__((address_space(3)))

typedef __bf16 bfrag  __attribute__((ext_vector_type(8)));
typedef float  ffrag  __attribute__((ext_vector_type(4)));
typedef __bf16 bf16x4 __attribute__((ext_vector_type(4)));

// ------- fused convert: x->bf16, W->bf16, zero rowsum (must precede scores) --
__global__ __launch_bounds__(256) void cvt_fused(const float* __restrict__ x,
                                                 const float* __restrict__ W,
                                                 __bf16* __restrict__ xb,
                                                 __bf16* __restrict__ Wb,
                                                 float* __restrict__ rowsum) {
  const int gid = blockIdx.x * 256 + threadIdx.x;
  const int stride = gridDim.x * 256;
  for (int k = gid; k < 4194304; k += stride) {
    float4 v = ((const float4*)x)[k];
    bf16x4 o;
    o[0] = (__bf16)v.x; o[1] = (__bf16)v.y; o[2] = (__bf16)v.z; o[3] = (__bf16)v.w;
    ((bf16x4*)xb)[k] = o;
  }
  for (int k = gid; k < 786432; k += stride) {
    float4 v = ((const float4*)W)[k];
    bf16x4 o;
    o[0] = (__bf16)v.x; o[1] = (__bf16)v.y; o[2] = (__bf16)v.z; o[3] = (__bf16)v.w;
    ((bf16x4*)Wb)[k] = o;
  }
  for (int k = gid; k < 16384; k += stride) rowsum[k] = 0.0f;
}

// =================== 256x256 8-phase single-barrier GEMM mainloop ============
__device__ __forceinline__ void stage_half(
    const __bf16* __restrict__ Atile, const __bf16* __restrict__ Btile,
    int lda, int ldb, __bf16* lds, int tid, int te, int h) {
  const int kt = te * 64;
  const __bf16* src = (h < 2) ? Atile : Btile;
  const int ld = (h < 2) ? lda : ldb;
  const int row0 = (h & 1) * 128;
  __bf16* dst = lds + (te & 1) * 32768 + h * 8192;
#pragma unroll
  for (int l = 0; l < 2; ++l) {
    const int y = l * 4096 + tid * 8;                  // linear LDS dest (uniform base + lane*16B)
    const int r = y >> 6;                              // row within half (0..127)
    const int c = ((tid & 7) * 8) ^ ((r & 7) << 3);    // inverse-swizzled source col
    __builtin_amdgcn_global_load_lds((AS1 void*)(src + (size_t)(row0 + r) * ld + kt + c),
                                     (AS3 void*)(dst + y), 16, 0, 0);
  }
}

template <int QA>
__device__ __forceinline__ void rd_a(const __bf16* lds, int bufoff, int aRowBase,
                                     int ck0, int ck1, bfrag a[4][2]) {
#pragma unroll
  for (int m = 0; m < 4; ++m) {
    const int off = bufoff + aRowBase + QA * 8192 + m * 1024;
    a[m][0] = *(const bfrag*)&lds[off + ck0];
    a[m][1] = *(const bfrag*)&lds[off + ck1];
  }
}

template <int QB>
__device__ __forceinline__ void rd_bq(const __bf16* lds, int bufoff, int bRowBase,
                                      int ck0, int ck1, bfrag b[2][2]) {
#pragma unroll
  for (int n = 0; n < 2; ++n) {
    const int off = bufoff + bRowBase + QB * 8192 + n * 1024;
    b[n][0] = *(const bfrag*)&lds[off + ck0];
    b[n][1] = *(const bfrag*)&lds[off + ck1];
  }
}

// Single-barrier phase tail: [vmcnt(6)] barrier; setprio 16 MFMA (compiler
// inserts fine-grained lgkmcnt per MFMA operand — no blanket drain).
#define PH(QA, QB, BREG, DOVM)                                                 \
  {                                                                            \
    if (DOVM) asm volatile("s_waitcnt vmcnt(6)" ::: "memory");                 \
    __builtin_amdgcn_s_barrier();                                              \
    __builtin_amdgcn_s_setprio(1);                                             \
    _Pragma("unroll") for (int m_ = 0; m_ < 4; ++m_)                           \
    _Pragma("unroll") for (int n_ = 0; n_ < 2; ++n_)                           \
    _Pragma("unroll") for (int ks_ = 0; ks_ < 2; ++ks_)                        \
      acc[(QA) * 4 + m_][(QB) * 2 + n_] =                                      \
          __builtin_amdgcn_mfma_f32_16x16x32_bf16(                             \
              a[m_][ks_], BREG[n_][ks_], acc[(QA) * 4 + m_][(QB) * 2 + n_],    \
              0, 0, 0);                                                        \
    __builtin_amdgcn_s_setprio(0);                                             \
  }

#define STG(TE, H) stage_half(Atile, Btile, lda, ldb, lds, tid, (TE), (H))

__device__ __forceinline__ void gemm256_mainloop(
    const __bf16* __restrict__ Atile, const __bf16* __restrict__ Btile,
    int lda, int ldb, int K, __bf16* lds, ffrag acc[8][4]) {
  const int tid  = threadIdx.x;
  const int lane = tid & 63;
  const int wid  = tid >> 6;
  const int wr   = wid >> 2, wc = wid & 3;
  const int fr   = lane & 15;
  const int fk   = (lane >> 4) * 8;
  const int swz  = (fr & 7) << 3;
  const int ck0  = fk ^ swz;            // ks=0 frag col (swizzled)
  const int ck1  = (32 + fk) ^ swz;     // ks=1
  const int aRowBase = (wr * 64 + fr) * 64;
  const int bRowBase = 16384 + (wc * 32 + fr) * 64;
  const int nT = K >> 6;

  // prologue: A0,B0,B1,A1 of T0; A0,B0,B1 of T1. vmcnt(6) -> T0 confirmed;
  // T1's 6 halves stay in flight (steady-state entry).
  STG(0, 0); STG(0, 2); STG(0, 3); STG(0, 1);
  STG(1, 0); STG(1, 2); STG(1, 3);
  asm volatile("s_waitcnt vmcnt(6)" ::: "memory");
  __builtin_amdgcn_s_barrier();

  const int nIter = nT >> 1;
#pragma unroll 1
  for (int i = 0; i < nIter; ++i) {
    const int t1  = 2 * i + 1;
    const int t2e = (2 * i + 2 < nT) ? (2 * i + 2) : (2 * i);      // tail wrap,
    const int t3e = (2 * i + 3 < nT) ? (2 * i + 3) : (2 * i + 1);  // same parity
    bfrag a[4][2], b0f[2][2], b1f[2][2];
    // P1: read a0+b0 (buf0); stage A1(t1) [buf1.A1, last read prev-P7: gap 2]
    rd_a<0>(lds, 0, aRowBase, ck0, ck1, a);
    rd_bq<0>(lds, 0, bRowBase, ck0, ck1, b0f);
    STG(t1, 1);
    PH(0, 0, b0f, false)
    // P2: read b1 (buf0); no stage
    rd_bq<1>(lds, 0, bRowBase, ck0, ck1, b1f);
    PH(0, 1, b1f, false)
    // P3: read a1 (buf0); stage A0(t2) [buf0.A0, read P1: gap 2]
    rd_a<1>(lds, 0, aRowBase, ck0, ck1, a);
    STG(t2e, 0);
    PH(1, 1, b1f, false)
    // P4: stage B0(t2) [read P1], B1(t2) [read P2]; vmcnt(6) -> T1 confirmed
    STG(t2e, 2);
    STG(t2e, 3);
    PH(1, 0, b0f, true)
    // P5: read a0+b0 (buf1); stage A1(t2) [buf0.A1, read P3: gap 2]
    rd_a<0>(lds, 32768, aRowBase, ck0, ck1, a);
    rd_bq<0>(lds, 32768, bRowBase, ck0, ck1, b0f);
    STG(t2e, 1);
    PH(0, 0, b0f, false)
    // P6: read b1 (buf1); no stage
    rd_bq<1>(lds, 32768, bRowBase, ck0, ck1, b1f);
    PH(0, 1, b1f, false)
    // P7: read a1 (buf1); stage A0(t3), B0(t3) [buf1.{A0,B0}, read P5: gap 2]
    rd_a<1>(lds, 32768, aRowBase, ck0, ck1, a);
    STG(t3e, 0);
    STG(t3e, 2);
    PH(1, 1, b1f, false)
    // P8: stage B1(t3) [read P6: gap 2]; vmcnt(6) -> t2 fully confirmed
    STG(t3e, 3);
    PH(1, 0, b0f, true)
  }
}

#define ACC_ZERO()                                                             \
  ffrag acc[8][4];                                                             \
  _Pragma("unroll") for (int m = 0; m < 8; ++m)                                \
  _Pragma("unroll") for (int n = 0; n < 4; ++n) acc[m][n] = (ffrag)(0.0f);

// Epilogue mapping for acc[i][j]: qa=i>>2, m=i&3, qb=j>>1, n=j&1.
// row = brow + qa*128 + wr*64 + m*16 + (lane>>4)*4 + r
// col = bcol + qb*128 + wc*32 + n*16 + (lane&15)

// ---------------- kernel 1: qkv projection (V written transposed) ----------
__global__ __launch_bounds__(512, 1) void qkv_gemm256(
    const __bf16* __restrict__ Abf, const __bf16* __restrict__ Wbf,
    const float* __restrict__ bias,
    __bf16* __restrict__ Q, __bf16* __restrict__ Ko, __bf16* __restrict__ Vt) {
  __shared__ __bf16 lds[65536];
  ACC_ZERO();
  // L2-locality order: XCD = bid&7 owns browTiles [8c,8c+8); within, 3 rounds
  // of 32 co-resident blocks forming 8-brow x 4-bcol supertiles (bijective).
  const int bid = (int)blockIdx.x;
  const int xc  = bid & 7;
  const int lid = bid >> 3;              // 0..95
  const int rr  = lid >> 5;              // concurrency round 0..2
  const int s   = lid & 31;              // 8 brow x 4 bcol
  const int brow = (xc * 8 + (s & 7)) * 256;
  const int bcol = (rr * 4 + (s >> 3)) * 256;
  gemm256_mainloop(Abf + (size_t)brow * 1024, Wbf + (size_t)bcol * 1024,
                   1024, 1024, 1024, lds, acc);
  const int lane = threadIdx.x & 63, wid = threadIdx.x >> 6;
  const int wr = wid >> 2, wc = wid & 3;
  const int region = bcol >> 10;              // 0=Q,1=K,2=V (tile within one region)
  if (region < 2) {
    __bf16* dst = region == 0 ? Q : Ko;
    const float scale = region == 0 ? 0.03125f : 1.0f;  // fold 1/sqrt(1024) into Q
#pragma unroll
    for (int j = 0; j < 4; ++j) {
      const int qb = j >> 1, n = j & 1;
      const int col = bcol + qb * 128 + wc * 32 + n * 16 + (lane & 15);
      const int o = col & 1023;
      const float bv = bias[col];
#pragma unroll
      for (int i = 0; i < 8; ++i) {
        const int qa = i >> 2, m = i & 3;
#pragma unroll
        for (int r = 0; r < 4; ++r) {
          const int mg = brow + qa * 128 + wr * 64 + m * 16 + (lane >> 4) * 4 + r;
          dst[(size_t)mg * 1024 + o] = (__bf16)((acc[i][j][r] + bv) * scale);
        }
      }
    }
  } else {
    // V: write transposed Vt[b][d][n]; 4 consecutive n-rows pack into one 8B store
#pragma unroll
    for (int j = 0; j < 4; ++j) {
      const int qb = j >> 1, n = j & 1;
      const int col = bcol + qb * 128 + wc * 32 + n * 16 + (lane & 15);
      const int o = col & 1023;                // d index
      const float bv = bias[col];
#pragma unroll
      for (int i = 0; i < 8; ++i) {
        const int qa = i >> 2, m = i & 3;
        const int mg0 = brow + qa * 128 + wr * 64 + m * 16 + (lane >> 4) * 4;
        const int b = mg0 >> 11, nr = mg0 & 2047;
        bf16x4 v;
#pragma unroll
        for (int r = 0; r < 4; ++r) v[r] = (__bf16)(acc[i][j][r] + bv);
        *(bf16x4*)&Vt[(size_t)b * 2097152 + (size_t)o * 2048 + nr] = v;
      }
    }
  }
}

// ------- kernel 2: Pu = exp(QK^T/32 - 16) bf16 + row-sum atomics -----------
__global__ __launch_bounds__(512, 1) void scores_gemm256(const __bf16* __restrict__ Q,
                                                         const __bf16* __restrict__ Kb,
                                                         __bf16* __restrict__ Pu,
                                                         float* __restrict__ rowsum) {
  __shared__ __bf16 lds[65536];
  ACC_ZERO();
  int bid = (int)blockIdx.x;                  // 512 blocks: XCD swizzle, batch-per-XCD
  const int wg = (bid & 7) * 64 + (bid >> 3);
  const int brow = (wg & 7) * 256, bcol = ((wg >> 3) & 7) * 256, z = wg >> 6;
  gemm256_mainloop(Q + (size_t)z * 2048 * 1024 + (size_t)brow * 1024,
                   Kb + (size_t)z * 2048 * 1024 + (size_t)bcol * 1024,
                   1024, 1024, 1024, lds, acc);
  const int lane = threadIdx.x & 63, wid = threadIdx.x >> 6;
  const int wr = wid >> 2, wc = wid & 3;
  const int fr = lane & 15, g4 = (lane >> 4) * 4;
#pragma unroll
  for (int i = 0; i < 8; ++i) {
    const int qa = i >> 2, m = i & 3;
#pragma unroll
    for (int r = 0; r < 4; ++r) {
      const int mg = brow + qa * 128 + wr * 64 + m * 16 + g4 + r;
      float part = 0.0f;
#pragma unroll
      for (int j = 0; j < 4; ++j) {
        const int qb = j >> 1, n = j & 1;
        const int o = bcol + qb * 128 + wc * 32 + n * 16 + fr;
        const float e = __expf(acc[i][j][r] - 16.0f);   // |S|<~6 -> e in bf16 range
        part += e;
        Pu[((size_t)(z * 2048 + mg)) * 2048 + o] = (__bf16)e;
      }
      // reduce the wave's 64-col partial across the 16 lanes sharing this row
      part += __shfl_xor(part, 1, 64);
      part += __shfl_xor(part, 2, 64);
      part += __shfl_xor(part, 4, 64);
      part += __shfl_xor(part, 8, 64);
      if (fr == 0) atomicAdd(&rowsum[z * 2048 + mg], part);
    }
  }
}

// ------- kernel 3: out = (Pu @ V) * 1/rowsum  (via Vt, B^T form) -----------
__global__ __launch_bounds__(512, 1) void pv_gemm256(const __bf16* __restrict__ P,
                                                     const __bf16* __restrict__ Vt,
                                                     const float* __restrict__ rowsum,
                                                     float* __restrict__ O) {
  __shared__ __bf16 lds[65536];
  ACC_ZERO();
  int bid = (int)blockIdx.x;                  // 256 blocks: XCD swizzle, batch-per-XCD
  const int wg = (bid & 7) * 32 + (bid >> 3);
  const int brow = (wg & 7) * 256, bcol = ((wg >> 3) & 3) * 256, z = wg >> 5;
  gemm256_mainloop(P + (size_t)(z * 2048 + brow) * 2048,
                   Vt + (size_t)z * 1024 * 2048 + (size_t)bcol * 2048,
                   2048, 2048, 2048, lds, acc);
  const int lane = threadIdx.x & 63, wid = threadIdx.x >> 6;
  const int wr = wid >> 2, wc = wid & 3;
  const int fr = lane & 15, g4 = (lane >> 4) * 4;
#pragma unroll
  for (int i = 0; i < 8; ++i) {
    const int qa = i >> 2, m = i & 3;
#pragma unroll
    for (int r = 0; r < 4; ++r) {
      const int mg = brow + qa * 128 + wr * 64 + m * 16 + g4 + r;
      const float inv = 1.0f / rowsum[z * 2048 + mg];
#pragma unroll
      for (int j = 0; j < 4; ++j) {
        const int qb = j >> 1, n = j & 1;
        const int o = bcol + qb * 128 + wc * 32 + n * 16 + fr;
        O[((size_t)(z * 2048 + mg)) * 1024 + o] = acc[i][j][r] * inv;
      }
    }
  }
}

extern "C" void kernel_launch(void* const* d_in, const int* in_sizes, int n_in,
                              void* d_out, int out_size, void* d_ws, size_t ws_size,
                              hipStream_t stream) {
  (void)in_sizes; (void)n_in; (void)out_size; (void)ws_size;
  const float* x    = (const float*)d_in[0];
  const float* W    = (const float*)d_in[1];
  const float* bias = (const float*)d_in[2];
  float* out = (float*)d_out;
  char* ws = (char*)d_ws;
  const size_t MB = 1u << 20;
  __bf16* x_bf = (__bf16*)(ws + 0);
  __bf16* W_bf = (__bf16*)(ws + 32 * MB);
  __bf16* Qb   = (__bf16*)(ws + 38 * MB);
  __bf16* Kb   = (__bf16*)(ws + 70 * MB);
  __bf16* Pu   = (__bf16*)(ws + 102 * MB);   // exp(S-16) bf16
  __bf16* Vt   = (__bf16*)(ws + 166 * MB);   // V^T, written by qkv epilogue
  float* rowsum = (float*)(ws + 198 * MB);   // f32[16384], zeroed by cvt_fused

  cvt_fused<<<2048, 256, 0, stream>>>(x, W, x_bf, W_bf, rowsum);
  qkv_gemm256<<<768, 512, 0, stream>>>(x_bf, W_bf, bias, Qb, Kb, Vt);
  scores_gemm256<<<512, 512, 0, stream>>>(Qb, Kb, Pu, rowsum);
  pv_gemm256<<<256, 512, 0, stream>>>(Pu, Vt, rowsum, out);
}